// Round 3
// baseline (172.314 us; speedup 1.0000x reference)
//
#include <hip/hip_runtime.h>
#include <stdint.h>

#define N 4096
#define B 2
#define D 128
#define LOG2E 1.4426950408889634f

typedef float f32x4 __attribute__((ext_vector_type(4)));

__device__ __forceinline__ float lrelu(float t) { return t > 0.f ? t : 0.01f * t; }

// K1: u_l[d] = sum_e Wa[e*D+d]*w_l[e]; u_r likewise. 1 block x 256 threads.
__global__ __launch_bounds__(256) void k1_uvec(
    const float* __restrict__ Wa,
    const float* __restrict__ w_l,
    const float* __restrict__ w_r,
    float* __restrict__ u) {          // u[0..D)=u_l, u[D..2D)=u_r
    __shared__ float2 pl[4][64];
    __shared__ float2 pr[4][64];
    int t = threadIdx.x;
    int d2 = t & 63;
    int h = t >> 6;
    const float2* Wa2 = (const float2*)Wa;
    float2 al = make_float2(0.f, 0.f), ar = make_float2(0.f, 0.f);
    #pragma unroll 8
    for (int k = 0; k < 32; ++k) {
        int e = h * 32 + k;
        float2 w = Wa2[e * 64 + d2];       // Wa[e, 2*d2], Wa[e, 2*d2+1]
        float wl = w_l[e];
        float wr = w_r[e];
        al.x += w.x * wl; al.y += w.y * wl;
        ar.x += w.x * wr; ar.y += w.y * wr;
    }
    pl[h][d2] = al; pr[h][d2] = ar;
    __syncthreads();
    if (t < 64) {
        float2 s = make_float2(0.f, 0.f);
        #pragma unroll
        for (int hh = 0; hh < 4; ++hh) { s.x += pl[hh][t].x; s.y += pl[hh][t].y; }
        ((float2*)u)[t] = s;
    } else if (t < 128) {
        int dd = t - 64;
        float2 s = make_float2(0.f, 0.f);
        #pragma unroll
        for (int hh = 0; hh < 4; ++hh) { s.x += pr[hh][dd].x; s.y += pr[hh][dd].y; }
        ((float2*)(u + D))[dd] = s;
    }
}

// K2: one wave per row. demands -> d_out, l -> lv, r -> colR. No atomics.
__global__ __launch_bounds__(256) void k2_rows(
    const float* __restrict__ x,     // [B*N, D]
    const float* __restrict__ Wd,    // [D]
    const float* __restrict__ bd,    // [1]
    const float* __restrict__ u,     // [2*D]
    float* __restrict__ out_dem,     // [B*N] (start of d_out)
    float* __restrict__ lv,          // [B*N]  l in exp2 domain
    float* __restrict__ colR) {      // [B*N]  r in exp2 domain
    int lane = threadIdx.x & 63;
    int row = blockIdx.x * 4 + (threadIdx.x >> 6);
    float2 xv = ((const float2*)(x + (size_t)row * D))[lane];
    float2 ul2 = ((const float2*)u)[lane];
    float2 ur2 = ((const float2*)(u + D))[lane];
    float2 wv = ((const float2*)Wd)[lane];
    float pl = xv.x * ul2.x + xv.y * ul2.y;
    float pr = xv.x * ur2.x + xv.y * ur2.y;
    float pd = xv.x * wv.x + xv.y * wv.y;
    #pragma unroll
    for (int m = 32; m >= 1; m >>= 1) {
        pl += __shfl_xor(pl, m, 64);
        pr += __shfl_xor(pr, m, 64);
        pd += __shfl_xor(pd, m, 64);
    }
    if (lane == 0) {
        float dem = 1.f / (1.f + __expf(-(pd + bd[0])));
        out_dem[row] = dem;
        lv[row] = pl * LOG2E;            // exp2 domain (lrelu commutes with pos. scale)
        colR[row] = pr * LOG2E;
    }
}

// K2b: one block per batch. Block-reduce rmax over 4096 r values (zero atomics),
// then write SoA column factors: colFp[j]=exp2(r-rmax), colFm[j]=exp2(0.01*(r-rmax)).
__global__ __launch_bounds__(1024) void k2b_fpm(
    const float* __restrict__ colR,
    float* __restrict__ colFp,
    float* __restrict__ colFm,
    float* __restrict__ gmax) {        // [B] rmax
    __shared__ float red[16];
    int b = blockIdx.x;
    int tid = threadIdx.x;
    const float* rb = colR + (size_t)b * N;
    float r[4];
    float m = -3.402823466e38f;
    #pragma unroll
    for (int k = 0; k < 4; ++k) {
        r[k] = rb[tid + k * 1024];
        m = fmaxf(m, r[k]);
    }
    #pragma unroll
    for (int s = 32; s >= 1; s >>= 1) m = fmaxf(m, __shfl_xor(m, s, 64));
    if ((tid & 63) == 0) red[tid >> 6] = m;
    __syncthreads();
    float rmax = red[0];
    #pragma unroll
    for (int w = 1; w < 16; ++w) rmax = fmaxf(rmax, red[w]);
    if (tid == 0) gmax[b] = rmax;
    #pragma unroll
    for (int k = 0; k < 4; ++k) {
        float t = r[k] - rmax;
        colFp[(size_t)b * N + tid + k * 1024] = exp2f(t);
        colFm[(size_t)b * N + tid + k * 1024] = exp2f(0.01f * t);
    }
}

// K2c: denominator pass. 4 rows/block. S1 = sum_{l+r>0} Fp_j, S2 = sum_else Fm_j.
// Writes rowfac[row] = (l, Ep*sc, Em*sc, 0) with sc = dem/(Ep*S1+Em*S2).
__global__ __launch_bounds__(256) void k2c_den(
    const float* __restrict__ lv,
    const float* __restrict__ colR,
    const float* __restrict__ colFp,
    const float* __restrict__ colFm,
    const float* __restrict__ gmax,
    const float* __restrict__ dem_f,
    float4* __restrict__ rowfac) {        // [B*N]
    __shared__ float red[4][8];
    int tid = threadIdx.x;
    int b = blockIdx.x >> 10;
    int i0 = (blockIdx.x & 1023) << 2;
    const float4* r4 = (const float4*)(colR + (size_t)b * N);
    const float4* p4 = (const float4*)(colFp + (size_t)b * N);
    const float4* m4 = (const float4*)(colFm + (size_t)b * N);
    float rmax = gmax[b];
    int rowbase = b * N + i0;

    float l_[4];
    #pragma unroll
    for (int q = 0; q < 4; ++q) l_[q] = lv[rowbase + q];

    float s1[4] = {0.f, 0.f, 0.f, 0.f}, s2[4] = {0.f, 0.f, 0.f, 0.f};
    #pragma unroll 4
    for (int k = 0; k < N / 4 / 256; ++k) {
        float4 rv = r4[tid + k * 256];
        float4 fp = p4[tid + k * 256];
        float4 fm = m4[tid + k * 256];
        #pragma unroll
        for (int q = 0; q < 4; ++q) {
            float l = l_[q];
            s1[q] += (l + rv.x > 0.f) ? fp.x : 0.f;
            s2[q] += (l + rv.x > 0.f) ? 0.f : fm.x;
            s1[q] += (l + rv.y > 0.f) ? fp.y : 0.f;
            s2[q] += (l + rv.y > 0.f) ? 0.f : fm.y;
            s1[q] += (l + rv.z > 0.f) ? fp.z : 0.f;
            s2[q] += (l + rv.z > 0.f) ? 0.f : fm.z;
            s1[q] += (l + rv.w > 0.f) ? fp.w : 0.f;
            s2[q] += (l + rv.w > 0.f) ? 0.f : fm.w;
        }
    }
    #pragma unroll
    for (int m = 32; m >= 1; m >>= 1) {
        #pragma unroll
        for (int q = 0; q < 4; ++q) {
            s1[q] += __shfl_xor(s1[q], m, 64);
            s2[q] += __shfl_xor(s2[q], m, 64);
        }
    }
    int w = tid >> 6;
    if ((tid & 63) == 0) {
        #pragma unroll
        for (int q = 0; q < 4; ++q) { red[w][q] = s1[q]; red[w][4 + q] = s2[q]; }
    }
    __syncthreads();
    if (tid < 4) {
        int q = tid;
        float S1 = red[0][q] + red[1][q] + red[2][q] + red[3][q];
        float S2 = red[0][4 + q] + red[1][4 + q] + red[2][4 + q] + red[3][4 + q];
        float t0 = l_[q] + rmax;
        float m0 = lrelu(t0);             // true row max of lrelu(l+r) (monotone)
        float Ep = exp2f(t0 - m0);
        float Em = exp2f(0.01f * t0 - m0);
        float sc = dem_f[rowbase + q] / (Ep * S1 + Em * S2);
        rowfac[rowbase + q] = make_float4(l_[q], Ep * sc, Em * sc, 0.f);
    }
}

// K3w: PURE linear streaming writer, mimicking the fill's access pattern:
// flat float4 index g; wave writes 1KB contiguous; consecutive waves contiguous.
// 8192 blocks x 256 threads x 4 grid-stride iters = 8,388,608 float4 = full output.
__global__ __launch_bounds__(256) void k3w_write(
    const float4* __restrict__ rowfac,   // [B*N] (l, EpSc, EmSc, -)
    const float* __restrict__ colR,      // [B*N]
    const float* __restrict__ colFp,
    const float* __restrict__ colFm,
    float* __restrict__ out_g) {         // [B,N,N] fp32, 16B-aligned
    const int STRIDE = 8192 * 256;       // float4s per sweep
    int g0 = blockIdx.x * 256 + threadIdx.x;
    #pragma unroll
    for (int it = 0; it < 4; ++it) {
        int g = g0 + it * STRIDE;
        int j4 = g & 1023;               // float4-column within row
        int i  = (g >> 10) & 4095;       // row
        int bb = g >> 22;                // batch
        float4 rf = rowfac[(bb << 12) + i];          // wave-uniform, L1-hot
        int cb = (bb << 12) + (j4 << 2);             // scalar col base b*N + 4*j4
        float4 rv = *(const float4*)(colR + cb);     // L1/L2-hot (16KB/batch each)
        float4 fp = *(const float4*)(colFp + cb);
        float4 fm = *(const float4*)(colFm + cb);
        f32x4 o;
        o.x = (rf.x + rv.x > 0.f) ? rf.y * fp.x : rf.z * fm.x;
        o.y = (rf.x + rv.y > 0.f) ? rf.y * fp.y : rf.z * fm.y;
        o.z = (rf.x + rv.z > 0.f) ? rf.y * fp.z : rf.z * fm.z;
        o.w = (rf.x + rv.w > 0.f) ? rf.y * fp.w : rf.z * fm.w;
        *((f32x4*)out_g + g) = o;
    }
}

extern "C" void kernel_launch(void* const* d_in, const int* in_sizes, int n_in,
                              void* d_out, int out_size, void* d_ws, size_t ws_size,
                              hipStream_t stream) {
    // inputs: 0 embed_feat(f32 B*N*D), 1 predict_G(int,ignored), 2 W_demand(f32 D),
    //         3 b_demand(f32 1), 4 Wa(f32 D*D), 5 w_l(f32 D), 6 w_r(f32 D)
    const float* x  = (const float*)d_in[0];
    const float* Wd = (const float*)d_in[2];
    const float* bd = (const float*)d_in[3];
    const float* Wa = (const float*)d_in[4];
    const float* wl = (const float*)d_in[5];
    const float* wr = (const float*)d_in[6];

    float* ws = (float*)d_ws;
    float* u      = ws;                       // 256 floats
    float* lv     = ws + 256;                 // 8192
    float* colR   = ws + 256 + 8192;          // 8192 (byte off 33792, 16B-aligned)
    float* colFp  = colR + 8192;              // 8192 (66560, 16B-aligned)
    float* colFm  = colFp + 8192;             // 8192 (99328, 16B-aligned)
    float4* rowfac = (float4*)(colFm + 8192); // 8192 float4 (132096, 16B-aligned)
    float* gmax   = (float*)(rowfac + 8192);  // 2 floats  (~263 KB total)

    float* out     = (float*)d_out;
    float* out_dem = out;           // [B*N]
    float* out_g   = out + B * N;   // [B,N,N] (byte off 32768, 16B-aligned)

    hipLaunchKernelGGL(k1_uvec, dim3(1), dim3(256), 0, stream, Wa, wl, wr, u);
    hipLaunchKernelGGL(k2_rows, dim3(B * N / 4), dim3(256), 0, stream,
                       x, Wd, bd, u, out_dem, lv, colR);
    hipLaunchKernelGGL(k2b_fpm, dim3(B), dim3(1024), 0, stream,
                       colR, colFp, colFm, gmax);
    hipLaunchKernelGGL(k2c_den, dim3(B * N / 4), dim3(256), 0, stream,
                       lv, colR, colFp, colFm, gmax, out_dem, rowfac);
    hipLaunchKernelGGL(k3w_write, dim3(8192), dim3(256), 0, stream,
                       rowfac, colR, colFp, colFm, out_g);
}

// Round 4
// 167.048 us; speedup vs baseline: 1.0315x; 1.0315x over previous
//
#include <hip/hip_runtime.h>
#include <stdint.h>

#define N 4096
#define B 2
#define D 128
#define LOG2E 1.4426950408889634f

typedef float f32x4 __attribute__((ext_vector_type(4)));

__device__ __forceinline__ float lrelu(float t) { return t > 0.f ? t : 0.01f * t; }

// K1: u_l[d] = sum_e Wa[e*D+d]*w_l[e]; u_r likewise. 1 block x 256 threads.
__global__ __launch_bounds__(256) void k1_uvec(
    const float* __restrict__ Wa,
    const float* __restrict__ w_l,
    const float* __restrict__ w_r,
    float* __restrict__ u) {          // u[0..D)=u_l, u[D..2D)=u_r
    __shared__ float2 pl[4][64];
    __shared__ float2 pr[4][64];
    int t = threadIdx.x;
    int d2 = t & 63;
    int h = t >> 6;
    const float2* Wa2 = (const float2*)Wa;
    float2 al = make_float2(0.f, 0.f), ar = make_float2(0.f, 0.f);
    #pragma unroll 8
    for (int k = 0; k < 32; ++k) {
        int e = h * 32 + k;
        float2 w = Wa2[e * 64 + d2];       // Wa[e, 2*d2], Wa[e, 2*d2+1]
        float wl = w_l[e];
        float wr = w_r[e];
        al.x += w.x * wl; al.y += w.y * wl;
        ar.x += w.x * wr; ar.y += w.y * wr;
    }
    pl[h][d2] = al; pr[h][d2] = ar;
    __syncthreads();
    if (t < 64) {
        float2 s = make_float2(0.f, 0.f);
        #pragma unroll
        for (int hh = 0; hh < 4; ++hh) { s.x += pl[hh][t].x; s.y += pl[hh][t].y; }
        ((float2*)u)[t] = s;
    } else if (t < 128) {
        int dd = t - 64;
        float2 s = make_float2(0.f, 0.f);
        #pragma unroll
        for (int hh = 0; hh < 4; ++hh) { s.x += pr[hh][dd].x; s.y += pr[hh][dd].y; }
        ((float2*)(u + D))[dd] = s;
    }
}

// K2: one wave per row. demands -> d_out, l -> lv, r -> colR. No atomics.
__global__ __launch_bounds__(256) void k2_rows(
    const float* __restrict__ x,     // [B*N, D]
    const float* __restrict__ Wd,    // [D]
    const float* __restrict__ bd,    // [1]
    const float* __restrict__ u,     // [2*D]
    float* __restrict__ out_dem,     // [B*N] (start of d_out)
    float* __restrict__ lv,          // [B*N]  l in exp2 domain
    float* __restrict__ colR) {      // [B*N]  r in exp2 domain
    int lane = threadIdx.x & 63;
    int row = blockIdx.x * 4 + (threadIdx.x >> 6);
    float2 xv = ((const float2*)(x + (size_t)row * D))[lane];
    float2 ul2 = ((const float2*)u)[lane];
    float2 ur2 = ((const float2*)(u + D))[lane];
    float2 wv = ((const float2*)Wd)[lane];
    float pl = xv.x * ul2.x + xv.y * ul2.y;
    float pr = xv.x * ur2.x + xv.y * ur2.y;
    float pd = xv.x * wv.x + xv.y * wv.y;
    #pragma unroll
    for (int m = 32; m >= 1; m >>= 1) {
        pl += __shfl_xor(pl, m, 64);
        pr += __shfl_xor(pr, m, 64);
        pd += __shfl_xor(pd, m, 64);
    }
    if (lane == 0) {
        float dem = 1.f / (1.f + __expf(-(pd + bd[0])));
        out_dem[row] = dem;
        lv[row] = pl * LOG2E;            // exp2 domain (lrelu commutes with pos. scale)
        colR[row] = pr * LOG2E;
    }
}

// K2b: one block per batch. Block-reduce rmax over 4096 r values (zero atomics),
// then write SoA column factors: colFp[j]=exp2(r-rmax), colFm[j]=exp2(0.01*(r-rmax)).
__global__ __launch_bounds__(1024) void k2b_fpm(
    const float* __restrict__ colR,
    float* __restrict__ colFp,
    float* __restrict__ colFm,
    float* __restrict__ gmax) {        // [B] rmax
    __shared__ float red[16];
    int b = blockIdx.x;
    int tid = threadIdx.x;
    const float* rb = colR + (size_t)b * N;
    float r[4];
    float m = -3.402823466e38f;
    #pragma unroll
    for (int k = 0; k < 4; ++k) {
        r[k] = rb[tid + k * 1024];
        m = fmaxf(m, r[k]);
    }
    #pragma unroll
    for (int s = 32; s >= 1; s >>= 1) m = fmaxf(m, __shfl_xor(m, s, 64));
    if ((tid & 63) == 0) red[tid >> 6] = m;
    __syncthreads();
    float rmax = red[0];
    #pragma unroll
    for (int w = 1; w < 16; ++w) rmax = fmaxf(rmax, red[w]);
    if (tid == 0) gmax[b] = rmax;
    #pragma unroll
    for (int k = 0; k < 4; ++k) {
        float t = r[k] - rmax;
        colFp[(size_t)b * N + tid + k * 1024] = exp2f(t);
        colFm[(size_t)b * N + tid + k * 1024] = exp2f(0.01f * t);
    }
}

// K2c: denominator pass. 4 rows/block. S1 = sum_{l+r>0} Fp_j, S2 = sum_else Fm_j.
// Writes rowfac[row] = (l, Ep*sc, Em*sc, 0) with sc = dem/(Ep*S1+Em*S2).
__global__ __launch_bounds__(256) void k2c_den(
    const float* __restrict__ lv,
    const float* __restrict__ colR,
    const float* __restrict__ colFp,
    const float* __restrict__ colFm,
    const float* __restrict__ gmax,
    const float* __restrict__ dem_f,
    float4* __restrict__ rowfac) {        // [B*N]
    __shared__ float red[4][8];
    int tid = threadIdx.x;
    int b = blockIdx.x >> 10;
    int i0 = (blockIdx.x & 1023) << 2;
    const float4* r4 = (const float4*)(colR + (size_t)b * N);
    const float4* p4 = (const float4*)(colFp + (size_t)b * N);
    const float4* m4 = (const float4*)(colFm + (size_t)b * N);
    float rmax = gmax[b];
    int rowbase = b * N + i0;

    float l_[4];
    #pragma unroll
    for (int q = 0; q < 4; ++q) l_[q] = lv[rowbase + q];

    float s1[4] = {0.f, 0.f, 0.f, 0.f}, s2[4] = {0.f, 0.f, 0.f, 0.f};
    #pragma unroll 4
    for (int k = 0; k < N / 4 / 256; ++k) {
        float4 rv = r4[tid + k * 256];
        float4 fp = p4[tid + k * 256];
        float4 fm = m4[tid + k * 256];
        #pragma unroll
        for (int q = 0; q < 4; ++q) {
            float l = l_[q];
            s1[q] += (l + rv.x > 0.f) ? fp.x : 0.f;
            s2[q] += (l + rv.x > 0.f) ? 0.f : fm.x;
            s1[q] += (l + rv.y > 0.f) ? fp.y : 0.f;
            s2[q] += (l + rv.y > 0.f) ? 0.f : fm.y;
            s1[q] += (l + rv.z > 0.f) ? fp.z : 0.f;
            s2[q] += (l + rv.z > 0.f) ? 0.f : fm.z;
            s1[q] += (l + rv.w > 0.f) ? fp.w : 0.f;
            s2[q] += (l + rv.w > 0.f) ? 0.f : fm.w;
        }
    }
    #pragma unroll
    for (int m = 32; m >= 1; m >>= 1) {
        #pragma unroll
        for (int q = 0; q < 4; ++q) {
            s1[q] += __shfl_xor(s1[q], m, 64);
            s2[q] += __shfl_xor(s2[q], m, 64);
        }
    }
    int w = tid >> 6;
    if ((tid & 63) == 0) {
        #pragma unroll
        for (int q = 0; q < 4; ++q) { red[w][q] = s1[q]; red[w][4 + q] = s2[q]; }
    }
    __syncthreads();
    if (tid < 4) {
        int q = tid;
        float S1 = red[0][q] + red[1][q] + red[2][q] + red[3][q];
        float S2 = red[0][4 + q] + red[1][4 + q] + red[2][4 + q] + red[3][4 + q];
        float t0 = l_[q] + rmax;
        float m0 = lrelu(t0);             // true row max of lrelu(l+r) (monotone)
        float Ep = exp2f(t0 - m0);
        float Em = exp2f(0.01f * t0 - m0);
        float sc = dem_f[rowbase + q] / (Ep * S1 + Em * S2);
        rowfac[rowbase + q] = make_float4(l_[q], Ep * sc, Em * sc, 0.f);
    }
}

// K3c: column-resident pure streaming writer.
// 1024 blocks x 256 threads = 4096 waves. Wave W = blk*4+w owns:
//   j-chunk jc = W & 15  -> lane's fixed float4-column j4 = jc*64+lane
//   row-group rg = W >> 4 -> 32 consecutive global rows (32 | 4096, so one batch)
// Column factors (r,Fp,Fm = 12 regs) loaded ONCE; inner loop per row:
//   1 wave-uniform 16B rowfac broadcast + ~16 VALU + one 1KB coalesced store.
// No per-store coalesced reads -> store pipe fed like the harness fill.
__global__ __launch_bounds__(256) void k3c_write(
    const float4* __restrict__ rowfac,   // [B*N] (l, EpSc, EmSc, -)
    const float* __restrict__ colR,
    const float* __restrict__ colFp,
    const float* __restrict__ colFm,
    float* __restrict__ out_g) {         // [B,N,N] fp32 (16B-aligned)
    int W = blockIdx.x * 4 + (threadIdx.x >> 6);
    int lane = threadIdx.x & 63;
    int jc = W & 15;
    int rg = W >> 4;                     // 0..255
    int row0 = rg * 32;                  // global row b*N+i; group stays in one batch
    int b = row0 >> 12;
    int j4 = jc * 64 + lane;             // float4-column 0..1023
    int cb = (b << 12) + (j4 << 2);
    float4 rv = *(const float4*)(colR + cb);
    float4 fp = *(const float4*)(colFp + cb);
    float4 fm = *(const float4*)(colFm + cb);
    f32x4* outp = (f32x4*)out_g + (size_t)row0 * 1024 + j4;
    #pragma unroll 8
    for (int k = 0; k < 32; ++k) {
        float4 rf = rowfac[row0 + k];    // uniform across wave -> L1 broadcast
        f32x4 o;
        o.x = (rf.x + rv.x > 0.f) ? rf.y * fp.x : rf.z * fm.x;
        o.y = (rf.x + rv.y > 0.f) ? rf.y * fp.y : rf.z * fm.y;
        o.z = (rf.x + rv.z > 0.f) ? rf.y * fp.z : rf.z * fm.z;
        o.w = (rf.x + rv.w > 0.f) ? rf.y * fp.w : rf.z * fm.w;
        outp[(size_t)k * 1024] = o;      // lanes cover 1KB contiguous of row row0+k
    }
}

extern "C" void kernel_launch(void* const* d_in, const int* in_sizes, int n_in,
                              void* d_out, int out_size, void* d_ws, size_t ws_size,
                              hipStream_t stream) {
    // inputs: 0 embed_feat(f32 B*N*D), 1 predict_G(int,ignored), 2 W_demand(f32 D),
    //         3 b_demand(f32 1), 4 Wa(f32 D*D), 5 w_l(f32 D), 6 w_r(f32 D)
    const float* x  = (const float*)d_in[0];
    const float* Wd = (const float*)d_in[2];
    const float* bd = (const float*)d_in[3];
    const float* Wa = (const float*)d_in[4];
    const float* wl = (const float*)d_in[5];
    const float* wr = (const float*)d_in[6];

    float* ws = (float*)d_ws;
    float* u      = ws;                       // 256 floats
    float* lv     = ws + 256;                 // 8192
    float* colR   = ws + 256 + 8192;          // 8192 (byte off 33792, 16B-aligned)
    float* colFp  = colR + 8192;              // 8192
    float* colFm  = colFp + 8192;             // 8192
    float4* rowfac = (float4*)(colFm + 8192); // 8192 float4 (16B-aligned)
    float* gmax   = (float*)(rowfac + 8192);  // 2 floats  (~263 KB total)

    float* out     = (float*)d_out;
    float* out_dem = out;           // [B*N]
    float* out_g   = out + B * N;   // [B,N,N] (byte off 32768, 16B-aligned)

    hipLaunchKernelGGL(k1_uvec, dim3(1), dim3(256), 0, stream, Wa, wl, wr, u);
    hipLaunchKernelGGL(k2_rows, dim3(B * N / 4), dim3(256), 0, stream,
                       x, Wd, bd, u, out_dem, lv, colR);
    hipLaunchKernelGGL(k2b_fpm, dim3(B), dim3(1024), 0, stream,
                       colR, colFp, colFm, gmax);
    hipLaunchKernelGGL(k2c_den, dim3(B * N / 4), dim3(256), 0, stream,
                       lv, colR, colFp, colFm, gmax, out_dem, rowfac);
    hipLaunchKernelGGL(k3c_write, dim3(1024), dim3(256), 0, stream,
                       rowfac, colR, colFp, colFm, out_g);
}